// Round 3
// baseline (498.702 us; speedup 1.0000x reference)
//
#include <hip/hip_runtime.h>

// Problem constants (fixed by reference)
#define BB 4
#define NN 4096
#define ROWS (BB*NN)     // 16384
#define KC 8             // k-split for spmm partials
#define KCH (NN/KC)      // 512 source rows per chunk
#define KT 64            // k-step within a chunk

typedef __attribute__((ext_vector_type(8))) short short8;
typedef __attribute__((ext_vector_type(4))) float f32x4;

__device__ __forceinline__ unsigned short f2bf(float f) {
    union { float f; unsigned int i; } cv; cv.f = f;
    unsigned int i = cv.i;
    return (unsigned short)((i + 0x7FFFu + ((i >> 16) & 1u)) >> 16);
}

// ---------------------------------------------------------------------------
// Kernel 1: pack adj -> bitmask. PURELY LINEAR read of the 268 MB (float4/lane,
// 1 KB per wave-instruction = same stream class as the 6.7 TB/s fills).
// Replaces all strided adj access forever: 268 MB -> 8 MB of bits.
// bitT[b][s][g][j] u64 (g = 256-col group, j = col%4): bit l <-> col g*256+4l+j
// (the natural __ballot permutation; the consumer un-permutes statically).
// ---------------------------------------------------------------------------
__global__ __launch_bounds__(256) void pack_bits(const float* __restrict__ adj,
                                                 unsigned long long* __restrict__ bitT) {
    int t  = threadIdx.x;
    int bi = blockIdx.x;           // 512 blocks: 4 b x 128 row-groups of 32
    int b  = bi >> 7;
    int s0 = (bi & 127) * 32;
    int wv = t >> 6, l = t & 63;   // wave covers cols [wv*1024, wv*1024+1024)
    const float* ab = adj + ((size_t)b * NN + s0) * NN;
    for (int i = 0; i < 32; ++i) {
        const float* row = ab + (size_t)i * NN + wv * 1024;
#pragma unroll
        for (int it = 0; it < 4; ++it) {
            float4 v = *(const float4*)(row + it * 256 + l * 4);
            unsigned long long m0 = __ballot(v.x != 0.0f);
            unsigned long long m1 = __ballot(v.y != 0.0f);
            unsigned long long m2 = __ballot(v.z != 0.0f);
            unsigned long long m3 = __ballot(v.w != 0.0f);
            if (l < 4) {
                unsigned long long w = (l == 0) ? m0 : (l == 1) ? m1 : (l == 2) ? m2 : m3;
                int g = wv * 4 + it;
                bitT[((size_t)(b * NN + s0 + i) << 6) + g * 4 + l] = w;
            }
        }
    }
}

// ---------------------------------------------------------------------------
// Kernel 2: fold weights -> WcatT bf16, B^T layout [n][k], n in [0,384):
//   n   0:128 -> Wu_top[k][n]; 128:256 -> (Wr@Wu_bot); 256:384 -> (Ws@Wu_bot)
// ---------------------------------------------------------------------------
__global__ __launch_bounds__(128) void fold_weights(const float* __restrict__ Wmsg,
                                                    const float* __restrict__ Wupd,
                                                    unsigned short* __restrict__ WcatT) {
    __shared__ float ldsS[128], ldsR[128];
    int k = blockIdx.x, t = threadIdx.x;
    ldsS[t] = Wmsg[k * 128 + t];            // Ws[k][t]
    ldsR[t] = Wmsg[(128 + k) * 128 + t];    // Wr[k][t]
    __syncthreads();
    float a1 = 0.f, a2 = 0.f;
#pragma unroll 8
    for (int m = 0; m < 128; ++m) {
        float wu = Wupd[(128 + m) * 128 + t];
        a1 += ldsS[m] * wu;
        a2 += ldsR[m] * wu;
    }
    WcatT[(size_t)t * 128 + k]         = f2bf(Wupd[k * 128 + t]);
    WcatT[(size_t)(128 + t) * 128 + k] = f2bf(a2);
    WcatT[(size_t)(256 + t) * 128 + k] = f2bf(a1);
}

// ---------------------------------------------------------------------------
// Kernel 3: MFMA GEMM: [T1|D2|YS] = x @ Wcat  (16384x128 @ 128x384)
// nb==2 writes YS transposed (YBT[b][n][s] bf16) via an LDS transpose tile
// (aliased over Al) -> coalesced 64 B stores (was 8 B @ 8 KB stride).
// ---------------------------------------------------------------------------
__global__ __launch_bounds__(256) void gemm_mfma(const float* __restrict__ X,
                                                 const unsigned short* __restrict__ WcatT,
                                                 float* __restrict__ TD,
                                                 unsigned short* __restrict__ YBT) {
    __shared__ __align__(16) char smem[18432 + 34816];
    unsigned short (*Al)[136] = (unsigned short (*)[136])smem;          // 64x136
    unsigned short (*Bl)[136] = (unsigned short (*)[136])(smem + 18432); // 128x136
    unsigned short (*Tl)[72]  = (unsigned short (*)[72])smem;           // 128x72, alias Al

    int t  = threadIdx.x;
    int m0 = blockIdx.x * 64;
    int nb = blockIdx.y;          // 0,1,2

    // stage A: 64 rows x 128 k fp32 -> bf16.
    {
        int m = t >> 2, seg = t & 3;
        const float* src = X + (size_t)(m0 + m) * 128 + seg * 32;
#pragma unroll
        for (int i = 0; i < 8; ++i) {
            float4 v = *(const float4*)(src + i * 4);
            ushort4 p;
            p.x = f2bf(v.x); p.y = f2bf(v.y); p.z = f2bf(v.z); p.w = f2bf(v.w);
            *(ushort4*)&Al[m][seg * 32 + i * 4] = p;
        }
    }
    // stage B: 128 rows x 128 k bf16 copy.
    {
        int n = t >> 1, half = t & 1;
        const unsigned short* src = WcatT + (size_t)(nb * 128 + n) * 128 + half * 64;
#pragma unroll
        for (int i = 0; i < 8; ++i) {
            uint4 v = *(const uint4*)(src + i * 8);
            *(uint4*)&Bl[n][half * 64 + i * 8] = v;
        }
    }
    __syncthreads();

    int lane = t & 63, wave = t >> 6;
    int quad = lane >> 4, lr = lane & 15;
    int wm = wave * 16;
    f32x4 acc[8];
#pragma unroll
    for (int s = 0; s < 8; ++s) acc[s] = (f32x4)0.f;

#pragma unroll
    for (int kk = 0; kk < 4; ++kk) {
        short8 a = *(short8*)&Al[wm + lr][kk * 32 + quad * 8];
#pragma unroll
        for (int s = 0; s < 8; ++s) {
            short8 bf = *(short8*)&Bl[s * 16 + lr][kk * 32 + quad * 8];
            acc[s] = __builtin_amdgcn_mfma_f32_16x16x32_bf16(a, bf, acc[s], 0, 0, 0);
        }
    }

    // epilogue: C/D mapping col = lane&15, row = quad*4 + reg  [m89/m91]
    if (nb == 2) {
        __syncthreads();               // all waves done reading Al -> reuse as Tl
#pragma unroll
        for (int s = 0; s < 8; ++s) {
            int n = s * 16 + lr;
            unsigned int p0 = (unsigned int)f2bf(acc[s][0]) | ((unsigned int)f2bf(acc[s][1]) << 16);
            unsigned int p1 = (unsigned int)f2bf(acc[s][2]) | ((unsigned int)f2bf(acc[s][3]) << 16);
            int m = wm + quad * 4;
            *(unsigned int*)&Tl[n][m]     = p0;
            *(unsigned int*)&Tl[n][m + 2] = p1;
        }
        __syncthreads();
        int n = t >> 1, half = t & 1;
        int b = m0 >> 12;
        int sbase = (m0 & (NN - 1)) + half * 32;
        const uint4* srcT = (const uint4*)&Tl[n][half * 32];
        uint4* dst = (uint4*)&YBT[(((size_t)(b << 7) + n) << 12) + sbase];
#pragma unroll
        for (int i = 0; i < 4; ++i) dst[i] = srcT[i];
    } else {
#pragma unroll
        for (int s = 0; s < 8; ++s)
#pragma unroll
            for (int r = 0; r < 4; ++r) {
                int row = m0 + wm + quad * 4 + r;
                TD[(size_t)row * 256 + nb * 128 + s * 16 + lr] = acc[s][r];
            }
    }
}

// ---------------------------------------------------------------------------
// Kernel 4: SpMM partials from the bitmask. Grid (16 rtiles, 8 kchunks, 4 b)
// = 512 blocks x 512 thr. Per block: bit slice (512 s x 256 r = 16 KB,
// L2/L3-resident) -> expand to bf16 0/1 tiles TRANSPOSED into XOR-swizzled
// LDS -> MFMA vs YBT (B-frags direct from L2). deg = exact bit count.
// No atomics: per-chunk partials, reduced by kernel 5.
// ---------------------------------------------------------------------------
__global__ __launch_bounds__(512, 4) void spmm_part(const unsigned long long* __restrict__ bitT,
                                                    const unsigned short* __restrict__ YBT,
                                                    float* __restrict__ Spart,
                                                    float* __restrict__ degPart) {
    __shared__ unsigned long long bwl64[KCH][4];   // 16 KB: whole chunk's bits
    __shared__ __align__(16) char Atb[256 * 128];  // 32 KB: [r][64k] bf16, XOR-swizzled

    int t  = threadIdx.x;
    int g  = blockIdx.x;          // r-group: 256 receivers
    int r0 = g * 256;
    int kc = blockIdx.y;
    int b  = blockIdx.z;

    // load chunk bitwords: s = t (512), 4 u64 each
    {
        const unsigned long long* src = bitT + ((size_t)(b * NN + kc * KCH) << 6) + g * 4;
#pragma unroll
        for (int j = 0; j < 4; ++j)
            bwl64[t][j] = src[(size_t)t * 64 + j];
    }

    // expansion constants: this thread owns receiver r (two threads per r)
    int r    = t >> 1;            // 0..255
    int kh   = t & 1;             // k-half of each 64-wide step
    int jj   = r & 3;             // ballot permutation: col = 4*l + j
    int sh   = r >> 2;            // ballot lane l = bit index
    int wsel = jj * 2 + (sh >> 5);  // u32 half of the u64 word
    int sh5  = sh & 31;
    const unsigned int* bw32 = (const unsigned int*)bwl64;   // [s][8]
    unsigned int dsum = 0;

    int lane = t & 63, wv = t >> 6;      // 8 waves, wave = 32 r x 128 n
    int quad = lane >> 4, lr = lane & 15;
    const unsigned short* yb = YBT + ((size_t)b << 19) + (size_t)kc * KCH;

    f32x4 acc[16];
#pragma unroll
    for (int i = 0; i < 16; ++i) acc[i] = (f32x4)0.f;

    for (int step = 0; step < KCH / KT; ++step) {   // 8 steps of K=64
        __syncthreads();          // prev MFMA done reading Atb (also orders bwl64 load)
        int sb = step * KT + kh * 32;
#pragma unroll
        for (int o = 0; o < 4; ++o) {
            short8 w;
#pragma unroll
            for (int e = 0; e < 8; ++e) {
                unsigned int word = bw32[(size_t)(sb + o * 8 + e) * 8 + wsel];
                unsigned int bit  = (word >> sh5) & 1u;
                dsum += bit;
                w[e] = bit ? (short)0x3F80 : (short)0;   // bf16 1.0 / 0.0 (exact)
            }
            int kbyte = (kh * 32 + o * 8) * 2;
            *(short8*)&Atb[r * 128 + (kbyte ^ ((r & 7) << 4))] = w;   // T2 swizzle
        }
        __syncthreads();
        // MFMA: A from swizzled LDS, B direct from global (L2-resident YBT)
#pragma unroll
        for (int kk = 0; kk < 2; ++kk) {
            int kbyte = kk * 64 + quad * 16;
            int ra0 = wv * 32 + lr, ra1 = wv * 32 + 16 + lr;
            short8 a0 = *(short8*)&Atb[ra0 * 128 + (kbyte ^ ((ra0 & 7) << 4))];
            short8 a1 = *(short8*)&Atb[ra1 * 128 + (kbyte ^ ((ra1 & 7) << 4))];
#pragma unroll
            for (int nf = 0; nf < 8; ++nf) {
                short8 bv = *(const short8*)(yb + (((size_t)(nf * 16 + lr)) << 12)
                                             + step * KT + kk * 32 + quad * 8);
                acc[nf * 2 + 0] = __builtin_amdgcn_mfma_f32_16x16x32_bf16(a0, bv, acc[nf * 2 + 0], 0, 0, 0);
                acc[nf * 2 + 1] = __builtin_amdgcn_mfma_f32_16x16x32_bf16(a1, bv, acc[nf * 2 + 1], 0, 0, 0);
            }
        }
    }

    // write partials: Spart[kc][row][n], coalesced 64 B segments
    float* sp = Spart + ((size_t)kc << 21) + (((size_t)(b * NN + r0)) << 7);
#pragma unroll
    for (int fr = 0; fr < 2; ++fr)
#pragma unroll
        for (int nf = 0; nf < 8; ++nf) {
            f32x4 a = acc[nf * 2 + fr];
#pragma unroll
            for (int rr = 0; rr < 4; ++rr) {
                int rl = wv * 32 + fr * 16 + quad * 4 + rr;
                sp[(size_t)rl * 128 + nf * 16 + lr] = a[rr];
            }
        }
    // exact per-chunk degree: pair (kh=0/1) sum via adjacent-lane shuffle
    unsigned int ds2 = dsum + __shfl_xor((int)dsum, 1, 64);
    if (kh == 0)
        degPart[((size_t)(kc * BB + b) << 12) + r0 + r] = (float)ds2;
}

// ---------------------------------------------------------------------------
// Kernel 5: reduce partials + epilogue: out = T1 + (deg>0)(D2 + S/deg)
// ---------------------------------------------------------------------------
__global__ __launch_bounds__(256) void reduce_out(const float* __restrict__ Spart,
                                                  const float* __restrict__ degPart,
                                                  const float* __restrict__ TD,
                                                  float* __restrict__ out) {
    int t   = threadIdx.x;
    int row = blockIdx.x * 2 + (t >> 7);
    int n   = t & 127;
    int b   = row >> 12;
    int r   = row & (NN - 1);
    float s = 0.f, deg = 0.f;
#pragma unroll
    for (int kc = 0; kc < KC; ++kc) {
        s   += Spart[((size_t)kc << 21) + ((size_t)row << 7) + n];
        deg += degPart[((size_t)(kc * BB + b) << 12) + r];
    }
    float v = TD[(size_t)row * 256 + n];
    if (deg > 0.f)
        v += TD[(size_t)row * 256 + 128 + n] + s / deg;
    out[(size_t)row * 128 + n] = v;
}

// ---------------------------------------------------------------------------
extern "C" void kernel_launch(void* const* d_in, const int* in_sizes, int n_in,
                              void* d_out, int out_size, void* d_ws, size_t ws_size,
                              hipStream_t stream) {
    const float* x    = (const float*)d_in[0];   // 16384 x 128
    const float* adj  = (const float*)d_in[1];   // 4 x 4096 x 4096
    const float* Wmsg = (const float*)d_in[2];   // 256 x 128
    const float* Wupd = (const float*)d_in[3];   // 256 x 128
    float* out = (float*)d_out;                  // 16384 x 128

    // workspace layout (bytes, aligned); total ~97 MB; all regions fully
    // rewritten every call (no memset / zero-init needed anywhere)
    char* ws = (char*)d_ws;
    unsigned short*     WcatT   = (unsigned short*)(ws);                    // 96 KB (128 KB resv)
    float*              TD      = (float*)(ws + 131072);                    // 16 MB
    unsigned short*     YBT     = (unsigned short*)(ws + 16908288);         // 4 MB  [b][n][s] bf16
    unsigned long long* bitT    = (unsigned long long*)(ws + 21102592);     // 8 MB  bitmask
    float*              Spart   = (float*)(ws + 29491200);                  // 64 MB [kc][row][n]
    float*              degPart = (float*)(ws + 96600064);                  // 512 KB [kc][b][r]

    pack_bits<<<512, 256, 0, stream>>>(adj, bitT);
    fold_weights<<<128, 128, 0, stream>>>(Wmsg, Wupd, WcatT);
    gemm_mfma<<<dim3(256, 3), 256, 0, stream>>>(x, WcatT, TD, YBT);
    spmm_part<<<dim3(16, KC, BB), 512, 0, stream>>>(bitT, YBT, Spart, degPart);
    reduce_out<<<ROWS / 2, 256, 0, stream>>>(Spart, degPart, TD, out);
}